// Round 8
// baseline (238.964 us; speedup 1.0000x reference)
//
#include <hip/hip_runtime.h>
#include <hip/hip_bf16.h>

#define NSEQ 2048
#define HID 128
#define HEADS 8
#define HD 16
#define SCALE 0.25f
#define SPLIT 8
#define KEYS_PER (NSEQ / SPLIT)   // 256 keys per block
#define NT (KEYS_PER / 16)        // 16 sixteen-key tiles
#define SB 132                    // bias LDS q-row stride in words ([h][m]=128 + 4 pad)
#define SKV 68                    // K/V LDS key-row stride in words (64 + 4 pad)

typedef unsigned short ushort_t;
typedef __attribute__((ext_vector_type(4))) short short4v;   // 4 bf16 (A/B frag, K=16 MFMA)
typedef __attribute__((ext_vector_type(4))) float floatx4;   // C/D frag
typedef __attribute__((ext_vector_type(4))) float f32x4;

// ---------------- kernel A: QKV projection ----------------
// grid 768 blocks x 128 threads; blocks [0,256)->Q (scaled bf16 hi/lo split),
// [256,512)->K bf16 rows, [512,768)->V bf16 rows (row-major Vm[n][j]).
__global__ __launch_bounds__(128) void qkv_kernel(
    const float* __restrict__ x, const float* __restrict__ Wq,
    const float* __restrict__ Wk, const float* __restrict__ Wv,
    const float* __restrict__ bq, const float* __restrict__ bk,
    const float* __restrict__ bv,
    __hip_bfloat16* __restrict__ Qh, __hip_bfloat16* __restrict__ Ql,
    __hip_bfloat16* __restrict__ Kb, __hip_bfloat16* __restrict__ Vm)
{
    __shared__ float xs[8 * HID];
    const int j = threadIdx.x;
    const int mat = blockIdx.x >> 8;
    const int rb = blockIdx.x & 255;
    const int r0 = rb * 8;
    const float* W = (mat == 0) ? Wq : (mat == 1) ? Wk : Wv;
    const float* bb = (mat == 0) ? bq : (mat == 1) ? bk : bv;
    const float4* xg = (const float4*)(x + (size_t)r0 * HID);
    float4* xl = (float4*)xs;
    for (int i = j; i < 8 * HID / 4; i += 128) xl[i] = xg[i];
    __syncthreads();
    float acc[8];
#pragma unroll
    for (int r = 0; r < 8; ++r) acc[r] = 0.f;
    const float4* Wrow = (const float4*)(W + (size_t)j * HID);
#pragma unroll 4
    for (int i4 = 0; i4 < HID / 4; ++i4) {
        float4 wv = Wrow[i4];
#pragma unroll
        for (int r = 0; r < 8; ++r) {
            float4 xv = *(const float4*)&xs[r * HID + i4 * 4];
            acc[r] = fmaf(xv.x, wv.x, acc[r]);
            acc[r] = fmaf(xv.y, wv.y, acc[r]);
            acc[r] = fmaf(xv.z, wv.z, acc[r]);
            acc[r] = fmaf(xv.w, wv.w, acc[r]);
        }
    }
    float bv_ = bb[j];
#pragma unroll
    for (int r = 0; r < 8; ++r) acc[r] += bv_;
    if (mat == 0) {
        // scaled hi/lo bf16 split: Qh + Ql represents acc*SCALE to ~2^-17 rel
#pragma unroll
        for (int r = 0; r < 8; ++r) {
            float qsv = acc[r] * SCALE;                 // exact (SCALE = 2^-2)
            __hip_bfloat16 hb = __float2bfloat16(qsv);
            float hf = __bfloat162float(hb);
            __hip_bfloat16 lb = __float2bfloat16(qsv - hf);
            Qh[(size_t)(r0 + r) * HID + j] = hb;
            Ql[(size_t)(r0 + r) * HID + j] = lb;
        }
    } else if (mat == 1) {
#pragma unroll
        for (int r = 0; r < 8; ++r) Kb[(size_t)(r0 + r) * HID + j] = __float2bfloat16(acc[r]);
    } else {
#pragma unroll
        for (int r = 0; r < 8; ++r) Vm[(size_t)(r0 + r) * HID + j] = __float2bfloat16(acc[r]);
    }
}

// ---------------- kernel B: fused attention, dense loads + depth-2 prefetch ----------------
// grid 1024 blocks x 256 threads (4 waves; wave = 2 heads x 16 q-rows x all keys).
// ALL global loads fully coalesced; redistribution via double-buffered LDS,
// ONE barrier per tile. DEPTH-2 register prefetch: regs for tile kt are loaded
// at iter kt-2 (named A/B sets, no dynamic indexing) -> prefetch distance = 2
// tile-periods, vmcnt stall at ds_write ~0 in steady state.
// S^T = K.Q^T via mfma_16x16x16_bf16, C preloaded with bias (ds_read_b128);
// S^T C-layout (lane holds P[key=4g+r][q=qi]) IS the A-frag layout for PV mfma.
__global__ __launch_bounds__(256, 4) void attn_kernel(
    const __hip_bfloat16* __restrict__ Qh, const __hip_bfloat16* __restrict__ Ql,
    const __hip_bfloat16* __restrict__ Kb, const __hip_bfloat16* __restrict__ Vm,
    const float* __restrict__ bias, const unsigned char* __restrict__ mask,
    float* __restrict__ Op, float* __restrict__ Lp)
{
    __shared__ float bsh[2][16 * SB];    // 16.9 KB bias [q][h][m]
    __shared__ float ksh[2][16 * SKV];   // 8.7 KB  K    [key][dim words]
    __shared__ float vsh[2][16 * SKV];   // 8.7 KB  V    [key][j words]

    const int t = threadIdx.x;
    const int lane = t & 63;
    const int wid = t >> 6;
    const int qi = lane & 15;          // q row (scores) / d col (PV out)
    const int g = lane >> 4;           // 0..3
    const int h0 = wid * 2;            // this wave's 2 heads

    const int qb = blockIdx.x & 127;
    const int sp = blockIdx.x >> 7;
    const int n0 = qb * 16;
    const int m0 = sp * KEYS_PER;

    // dense staging roles
    const int bq = t >> 5;             // 0..7  (bias rows, 2 instrs cover 16)
    const int bc = t & 31;             // 0..31 (16B chunk within 512B row)
    const int kq = t >> 4;             // 0..15 (K/V key row)
    const int kc = t & 15;             // 0..15 (16B chunk within 256B row)

    const float* bA = bias + ((size_t)(n0 + bq) * NSEQ + m0) * HEADS + bc * 4;
    const float* bB = bias + ((size_t)(n0 + 8 + bq) * NSEQ + m0) * HEADS + bc * 4;
    const ushort_t* kG = (const ushort_t*)Kb + (size_t)(m0 + kq) * HID + kc * 8;
    const ushort_t* vG = (const ushort_t*)Vm + (size_t)(m0 + kq) * HID + kc * 8;

    // bias LDS write decomposition: chunk bc = floats {4bc..4bc+3} of [m][h] row
    // -> m = bc>>1, h = 4*(bc&1)+k  =>  word q*SB + h*16 + m
    const int bm = bc >> 1;
    const int bh = 4 * (bc & 1);
    const int wA = bq * SB + bh * 16 + bm;
    const int wB = (8 + bq) * SB + bh * 16 + bm;
    const int wK = kq * SKV + kc * 4;

    // Q B-fragments for 2 heads (hi/lo): B[k=dim 4g+i][col=q=qi]
    short4v qhf[2], qlf[2];
#pragma unroll
    for (int hh = 0; hh < 2; ++hh) {
        const size_t qoff = (size_t)(n0 + qi) * HID + (h0 + hh) * HD + 4 * g;
        qhf[hh] = *(const short4v*)((const ushort_t*)Qh + qoff);
        qlf[hh] = *(const short4v*)((const ushort_t*)Ql + qoff);
    }

    floatx4 o[2];
    o[0] = (floatx4){0.f, 0.f, 0.f, 0.f};
    o[1] = (floatx4){0.f, 0.f, 0.f, 0.f};
    float lrun[2] = {0.f, 0.f};

    // two named in-flight register sets: A = even tiles, B = odd tiles
    f32x4 A_b0, A_b1, A_k, A_v;
    f32x4 B_b0, B_b1, B_k, B_v;

    // prologue: load tiles 0 (A) and 1 (B)
    A_b0 = *(const f32x4*)bA;
    A_b1 = *(const f32x4*)bB;
    A_k  = *(const f32x4*)kG;
    A_v  = *(const f32x4*)vG;
    B_b0 = *(const f32x4*)(bA + 16 * HEADS);
    B_b1 = *(const f32x4*)(bB + 16 * HEADS);
    B_k  = *(const f32x4*)(kG + (size_t)16 * HID);
    B_v  = *(const f32x4*)(vG + (size_t)16 * HID);

    // per-tile compute, reading from LDS buffer `buf`
    auto compute = [&](int kt, int buf) {
        float* Bs = &bsh[buf][0];
        float* Ks = &ksh[buf][0];
        float* Vs = &vsh[buf][0];
        const int m1 = m0 + kt * 16;
        const uchar4 mk = *(const uchar4*)(mask + m1 + 4 * g);
        const ushort_t* vw = (const ushort_t*)Vs;
#pragma unroll
        for (int hh = 0; hh < 2; ++hh) {
            const int h = h0 + hh;
            // C init: b128 -> bias[n0+qi][m1+4g+r][h], conflict-free
            floatx4 s = *(const f32x4*)&Bs[qi * SB + h * 16 + 4 * g];
            // K A-fragment: b64 -> K[m1+qi][h*16+4g..+3], conflict-free
            short4v ka = *(const short4v*)&Ks[qi * SKV + h * 8 + 2 * g];
            // S^T = (K.Qh^T + K.Ql^T) + bias  (SCALE folded into Qh/Ql)
            s = __builtin_amdgcn_mfma_f32_16x16x16bf16_1k(ka, qhf[hh], s, 0, 0, 0);
            s = __builtin_amdgcn_mfma_f32_16x16x16bf16_1k(ka, qlf[hh], s, 0, 0, 0);
            float e0 = mk.x ? 0.f : __expf(s.x);
            float e1 = mk.y ? 0.f : __expf(s.y);
            float e2 = mk.z ? 0.f : __expf(s.z);
            float e3 = mk.w ? 0.f : __expf(s.w);
            lrun[hh] += (e0 + e1) + (e2 + e3);
            // P A-fragment for PV (lane already holds P[q=qi][key=4g+r])
            __hip_bfloat16 p0 = __float2bfloat16(e0);
            __hip_bfloat16 p1 = __float2bfloat16(e1);
            __hip_bfloat16 p2 = __float2bfloat16(e2);
            __hip_bfloat16 p3 = __float2bfloat16(e3);
            short4v pa = {(short)*(ushort_t*)&p0, (short)*(ushort_t*)&p1,
                          (short)*(ushort_t*)&p2, (short)*(ushort_t*)&p3};
            // V B-fragment: 4x ds_read_u16: B[k=key 4g+i][col=d=qi] = V[m1+4g+i][h*16+qi]
            ushort_t e0v = vw[(4 * g + 0) * (2 * SKV) + h * 16 + qi];
            ushort_t e1v = vw[(4 * g + 1) * (2 * SKV) + h * 16 + qi];
            ushort_t e2v = vw[(4 * g + 2) * (2 * SKV) + h * 16 + qi];
            ushort_t e3v = vw[(4 * g + 3) * (2 * SKV) + h * 16 + qi];
            short4v vb = {(short)e0v, (short)e1v, (short)e2v, (short)e3v};
            o[hh] = __builtin_amdgcn_mfma_f32_16x16x16bf16_1k(pa, vb, o[hh], 0, 0, 0);
        }
    };

    for (int kt = 0; kt < NT; kt += 2) {
        // ---- even tile kt (register set A, LDS buffer 0) ----
        {
            float* Bs = &bsh[0][0];
            Bs[wA]      = A_b0.x; Bs[wA + 16] = A_b0.y;
            Bs[wA + 32] = A_b0.z; Bs[wA + 48] = A_b0.w;
            Bs[wB]      = A_b1.x; Bs[wB + 16] = A_b1.y;
            Bs[wB + 32] = A_b1.z; Bs[wB + 48] = A_b1.w;
            *(f32x4*)&ksh[0][wK] = A_k;
            *(f32x4*)&vsh[0][wK] = A_v;
            __syncthreads();
            if (kt + 2 < NT) {   // reissue set A for tile kt+2 (consumed in 2 iters)
                A_b0 = *(const f32x4*)(bA + (kt + 2) * (16 * HEADS));
                A_b1 = *(const f32x4*)(bB + (kt + 2) * (16 * HEADS));
                A_k  = *(const f32x4*)(kG + (size_t)(kt + 2) * 16 * HID);
                A_v  = *(const f32x4*)(vG + (size_t)(kt + 2) * 16 * HID);
            }
            compute(kt, 0);
        }
        // ---- odd tile kt+1 (register set B, LDS buffer 1) ----
        {
            float* Bs = &bsh[1][0];
            Bs[wA]      = B_b0.x; Bs[wA + 16] = B_b0.y;
            Bs[wA + 32] = B_b0.z; Bs[wA + 48] = B_b0.w;
            Bs[wB]      = B_b1.x; Bs[wB + 16] = B_b1.y;
            Bs[wB + 32] = B_b1.z; Bs[wB + 48] = B_b1.w;
            *(f32x4*)&ksh[1][wK] = B_k;
            *(f32x4*)&vsh[1][wK] = B_v;
            __syncthreads();
            if (kt + 3 < NT) {   // reissue set B for tile kt+3
                B_b0 = *(const f32x4*)(bA + (kt + 3) * (16 * HEADS));
                B_b1 = *(const f32x4*)(bB + (kt + 3) * (16 * HEADS));
                B_k  = *(const f32x4*)(kG + (size_t)(kt + 3) * 16 * HID);
                B_v  = *(const f32x4*)(vG + (size_t)(kt + 3) * 16 * HID);
            }
            compute(kt + 1, 1);
        }
    }

    // ---- epilogue: O partials (lane holds O[q=4g+r][d=qi]) + l partials ----
#pragma unroll
    for (int hh = 0; hh < 2; ++hh) {
        lrun[hh] += __shfl_xor(lrun[hh], 16);  // sum over g
        lrun[hh] += __shfl_xor(lrun[hh], 32);
        const int h = h0 + hh;
#pragma unroll
        for (int r = 0; r < 4; ++r)
            Op[((size_t)(n0 + 4 * g + r) * SPLIT + sp) * HID + h * HD + qi] = o[hh][r];
        if (g == 0)
            Lp[((size_t)(n0 + qi) * SPLIT + sp) * HEADS + h] = lrun[hh];
    }
}

// ---------------- kernel C: combine splits + output projection ----------------
// grid 512 blocks x 128 threads, 4 rows per block
__global__ __launch_bounds__(128) void proj_kernel(
    const float* __restrict__ Op, const float* __restrict__ Lp,
    const float* __restrict__ Wo, const float* __restrict__ bo,
    float* __restrict__ out)
{
    __shared__ float xs[4 * HID];
    const int j = threadIdx.x;
    const int r0 = blockIdx.x * 4;
    const int hh = j >> 4;
#pragma unroll
    for (int r = 0; r < 4; ++r) {
        const size_t n = r0 + r;
        float s = 0.f, l = 0.f;
#pragma unroll
        for (int sp = 0; sp < SPLIT; ++sp) {
            s += Op[(n * SPLIT + sp) * HID + j];
            l += Lp[(n * SPLIT + sp) * HEADS + hh];
        }
        xs[r * HID + j] = s / l;
    }
    __syncthreads();
    float acc[4];
#pragma unroll
    for (int r = 0; r < 4; ++r) acc[r] = 0.f;
    const float4* Wrow = (const float4*)(Wo + (size_t)j * HID);
#pragma unroll 4
    for (int i4 = 0; i4 < HID / 4; ++i4) {
        float4 wv = Wrow[i4];
#pragma unroll
        for (int r = 0; r < 4; ++r) {
            float4 xv = *(const float4*)&xs[r * HID + i4 * 4];
            acc[r] = fmaf(xv.x, wv.x, acc[r]);
            acc[r] = fmaf(xv.y, wv.y, acc[r]);
            acc[r] = fmaf(xv.z, wv.z, acc[r]);
            acc[r] = fmaf(xv.w, wv.w, acc[r]);
        }
    }
    float b = bo[j];
#pragma unroll
    for (int r = 0; r < 4; ++r)
        out[(size_t)(r0 + r) * HID + j] = acc[r] + b;
}

extern "C" void kernel_launch(void* const* d_in, const int* in_sizes, int n_in,
                              void* d_out, int out_size, void* d_ws, size_t ws_size,
                              hipStream_t stream) {
    const float* x    = (const float*)d_in[0];
    const float* bias = (const float*)d_in[1];
    const unsigned char* mask = (const unsigned char*)d_in[2];
    const float* Wq = (const float*)d_in[3];
    const float* bq = (const float*)d_in[4];
    const float* Wk = (const float*)d_in[5];
    const float* bk = (const float*)d_in[6];
    const float* Wv = (const float*)d_in[7];
    const float* bv = (const float*)d_in[8];
    const float* Wo = (const float*)d_in[9];
    const float* bo = (const float*)d_in[10];
    float* out = (float*)d_out;

    float* w = (float*)d_ws;
    // ws layout (float offsets):
    __hip_bfloat16* Qh = (__hip_bfloat16*)(w);           // 262144 bf16
    __hip_bfloat16* Ql = (__hip_bfloat16*)(w + 131072);  // 262144 bf16
    __hip_bfloat16* Kb = (__hip_bfloat16*)(w + 262144);  // 262144 bf16 rows [n][j]
    __hip_bfloat16* Vm = (__hip_bfloat16*)(w + 393216);  // 262144 bf16 rows [n][j]
    float* Op  = w + 524288;                             // NSEQ*SPLIT*HID fp32 (8 MB), [n][sp][hd]
    float* Lp  = w + 524288 + (size_t)NSEQ * SPLIT * HID; // [n][sp][h]
    // total ~11 MB

    qkv_kernel<<<768, 128, 0, stream>>>(x, Wq, Wk, Wv, bq, bk, bv, Qh, Ql, Kb, Vm);
    attn_kernel<<<128 * SPLIT, 256, 0, stream>>>(Qh, Ql, Kb, Vm, bias, mask, Op, Lp);
    proj_kernel<<<512, 128, 0, stream>>>(Op, Lp, Wo, bo, out);
}